// Round 6
// baseline (513.943 us; speedup 1.0000x reference)
//
#include <hip/hip_runtime.h>
#include <math.h>

#define B_ 32
#define C_ 3
#define H_ 512
#define W_ 512
#define NOUT 64
#define FAN (C_*H_*W_)          // 786432

#define CHUNKS 192
#define CELEMS (FAN / CHUNKS)   // 4096
#define GRID 768                // = 192 chunks x 4 bgroups = 8 hc x 96 bc

// workspace layout (floats):
//   [0, 30720): per-chunk locnet partials P[chunk][b][j] (stride 160)
//   [PF_OFF, +256): pf[b][8] = {p0..p3 biased, gamma, pad}
//   [BAR_OFF, +2): grid-barrier {cnt, gen} (uint), zeroed by captured memset
//   ushort images at ws + PFLOATS floats: FxH, FxL, FyH, FyL (1,048,576 ushorts each)
#define PPART_STRIDE 160
#define PF_OFF (CHUNKS * PPART_STRIDE)   // 30720
#define BAR_OFF 31000
#define PFLOATS 32768
#define FXH_U 0
#define FXL_U 1048576
#define FYH_U 2097152
#define FYL_U 3145728

typedef __bf16 bf16x8 __attribute__((ext_vector_type(8)));
typedef float f32x4 __attribute__((ext_vector_type(4)));

__device__ __forceinline__ unsigned short f2bf(float f) {
    unsigned int u = __float_as_uint(f);
    u = (u + 0x7FFFu + ((u >> 16) & 1u)) >> 16;
    return (unsigned short)u;
}
__device__ __forceinline__ float bf2f(unsigned short h) {
    return __uint_as_float(((unsigned int)h) << 16);
}
__device__ __forceinline__ unsigned int cvt_pk_bf16(float lo, float hi) {
    unsigned int r;
    asm("v_cvt_pk_bf16_f32 %0, %1, %2" : "=v"(r) : "v"(lo), "v"(hi));
    return r;
}

union BF8U { uint4 u; bf16x8 v; };

// sense-reversing grid barrier; all 768 blocks resident by construction
// (LDS 36.9KB -> 4 blk/CU, launch_bounds(256,4) -> 16 waves/CU; 1024 >= 768).
__device__ __forceinline__ void grid_barrier(unsigned* bar, int t) {
    __syncthreads();
    if (t == 0) {
        unsigned g = __hip_atomic_load(&bar[1], __ATOMIC_RELAXED, __HIP_MEMORY_SCOPE_AGENT);
        __threadfence();
        unsigned arrived = __hip_atomic_fetch_add(&bar[0], 1u, __ATOMIC_ACQ_REL,
                                                  __HIP_MEMORY_SCOPE_AGENT) + 1u;
        if (arrived == (unsigned)GRID) {
            __hip_atomic_store(&bar[0], 0u, __ATOMIC_RELAXED, __HIP_MEMORY_SCOPE_AGENT);
            __hip_atomic_fetch_add(&bar[1], 1u, __ATOMIC_RELEASE, __HIP_MEMORY_SCOPE_AGENT);
        } else {
            long cap = 0;
            while (__hip_atomic_load(&bar[1], __ATOMIC_ACQUIRE,
                                     __HIP_MEMORY_SCOPE_AGENT) == g) {
                if (++cap > (1L << 31)) break;   // failsafe: fail, don't hang
            }
        }
        __threadfence();
    }
    __syncthreads();
}

#define KC 64
#define PITCH 72            // ushorts per LDS row
#define TSZ (64 * PITCH)    // 4608 ushorts per array

__global__ __launch_bounds__(256, 4) void k_fused(const float* __restrict__ X,
                                                  const float* __restrict__ Wl,
                                                  const float* __restrict__ bl,
                                                  float* __restrict__ ws,
                                                  float* __restrict__ out) {
    const int bid = blockIdx.x;
    const int t = threadIdx.x;
    const int lane = t & 63;
    const int wave = t >> 6;
    unsigned* bar = (unsigned*)(ws + BAR_OFF);

    __shared__ __align__(16) unsigned short lds[4 * TSZ];   // 36864 B
    __shared__ float sred[4][40];
    __shared__ float sredB[4];
    __shared__ float stot;

    // ================= Phase A: locnet partials =================
    {
        const int chunk = bid >> 2;        // 0..191
        const int b0 = (bid & 3) * 8;      // 0,8,16,24
        float acc[8][5] = {};
        const size_t base = (size_t)chunk * CELEMS;

        for (int k = t; k < CELEMS / 4; k += 256) {   // 4 iterations
            const size_t i0 = base + (size_t)k * 4;
            const float4* W4 = (const float4*)(Wl + i0 * 5);
            float4 w0 = W4[0], w1 = W4[1], w2 = W4[2], w3 = W4[3], w4 = W4[4];
            float wv[20] = {w0.x, w0.y, w0.z, w0.w,
                            w1.x, w1.y, w1.z, w1.w,
                            w2.x, w2.y, w2.z, w2.w,
                            w3.x, w3.y, w3.z, w3.w,
                            w4.x, w4.y, w4.z, w4.w};
            #pragma unroll
            for (int bb = 0; bb < 8; bb++) {
                float4 x = *(const float4*)(X + (size_t)(b0 + bb) * FAN + i0);
                float xv[4] = {x.x, x.y, x.z, x.w};
                #pragma unroll
                for (int e = 0; e < 4; e++)
                    #pragma unroll
                    for (int j = 0; j < 5; j++)
                        acc[bb][j] += xv[e] * wv[e * 5 + j];
            }
        }

        #pragma unroll
        for (int off = 32; off > 0; off >>= 1)
            #pragma unroll
            for (int bb = 0; bb < 8; bb++)
                #pragma unroll
                for (int j = 0; j < 5; j++)
                    acc[bb][j] += __shfl_down(acc[bb][j], off);

        if (lane == 0) {
            #pragma unroll
            for (int bb = 0; bb < 8; bb++)
                #pragma unroll
                for (int j = 0; j < 5; j++)
                    sred[wave][bb * 5 + j] = acc[bb][j];
        }
        __syncthreads();
        if (t < 40) {
            float s = sred[0][t] + sred[1][t] + sred[2][t] + sred[3][t];
            ws[(size_t)chunk * PPART_STRIDE + b0 * 5 + t] = s;
        }
    }
    grid_barrier(bar, t);

    // ================= Phase B0: reduce partials -> pf[b][.] =================
    if (bid < B_) {
        const int b = bid;
        float pj[5] = {0.f, 0.f, 0.f, 0.f, 0.f};
        if (t < CHUNKS) {
            const float* pr = ws + (size_t)t * PPART_STRIDE + b * 5;
            #pragma unroll
            for (int j = 0; j < 5; j++) pj[j] = pr[j];
        }
        #pragma unroll
        for (int off = 32; off > 0; off >>= 1)
            #pragma unroll
            for (int j = 0; j < 5; j++) pj[j] += __shfl_down(pj[j], off);
        if (lane == 0) {
            #pragma unroll
            for (int j = 0; j < 5; j++) sred[wave][j] = pj[j];
        }
        __syncthreads();
        if (t < 5) {
            float v = sred[0][t] + sred[1][t] + sred[2][t] + sred[3][t] + bl[t];
            ws[PF_OFF + b * 8 + t] = (t == 4) ? expf(v) : v;
        }
    }
    grid_barrier(bar, t);

    // ================= Phase B: filters (bf16 hi/lo) + zero out =================
    for (int u = bid; u < 2 * B_ * NOUT; u += GRID) {   // 4096 units
        const int which = u >> 11;
        const int b = (u >> 6) & 31;
        const int n = u & 63;

        if (t < 24)
            ((float4*)out)[(size_t)u * 24 + t] = make_float4(0.f, 0.f, 0.f, 0.f);

        const float p0 = ws[PF_OFF + b * 8 + 0];
        const float p1 = ws[PF_OFF + b * 8 + 1];
        const float p2 = ws[PF_OFF + b * 8 + 2];
        const float p3 = ws[PF_OFF + b * 8 + 3];

        const float g = (which == 0) ? 32.f * (p0 + 1.f) : 32.f * (p1 + 1.f);
        const float sigma2 = expf(p2);
        const float inv2s = 0.5f / sigma2;
        const float delta = expf(p3) * (511.0f / 63.0f);
        const float mean = g + delta * ((float)n - 32.5f);

        float d0 = (float)(2 * t) - mean;
        float f0 = expf(-d0 * d0 * inv2s);
        float d1 = (float)(2 * t + 1) - mean;
        float f1 = expf(-d1 * d1 * inv2s);

        float s = f0 + f1;
        #pragma unroll
        for (int off = 32; off > 0; off >>= 1) s += __shfl_down(s, off);
        if (lane == 0) sredB[wave] = s;
        __syncthreads();
        if (t == 0) stot = sredB[0] + sredB[1] + sredB[2] + sredB[3] + 1e-4f;
        __syncthreads();
        const float scale = 1.0f / stot;

        unsigned short* wsu = (unsigned short*)(ws + PFLOATS);
        unsigned int* dstH = (unsigned int*)(wsu + (which ? FYH_U : FXH_U) + ((size_t)b * NOUT + n) * 512);
        unsigned int* dstL = (unsigned int*)(wsu + (which ? FYL_U : FXL_U) + ((size_t)b * NOUT + n) * 512);

        float v0 = f0 * scale;
        float v1 = f1 * scale;
        unsigned short h0 = f2bf(v0);
        unsigned short h1 = f2bf(v1);
        unsigned short l0 = f2bf(v0 - bf2f(h0));
        unsigned short l1 = f2bf(v1 - bf2f(h1));
        dstH[t] = (unsigned int)h0 | ((unsigned int)h1 << 16);
        dstL[t] = (unsigned int)l0 | ((unsigned int)l1 << 16);
        __syncthreads();
    }
    grid_barrier(bar, t);

    // ================= Phase C: MFMA glimpse (R3 structure) =================
    {
        const int hc = bid & 7;       // 0..7
        const int bc = bid >> 3;      // 0..95
        const int b = bc / 3;
        const int wv = wave;
        const int l15 = lane & 15;
        const int quad = lane >> 4;
        const int hbase = hc * 64;

        unsigned short* Xh = lds;
        unsigned short* Xl = lds + TSZ;
        unsigned short* Fh = lds + 2 * TSZ;
        unsigned short* Fl = lds + 3 * TSZ;

        const float* Xp = X + (size_t)bc * (H_ * W_) + (size_t)hbase * W_;
        const unsigned short* wsu = (const unsigned short*)(ws + PFLOATS);
        const unsigned short* FxHp = wsu + FXH_U + (size_t)b * NOUT * 512;
        const unsigned short* FxLp = wsu + FXL_U + (size_t)b * NOUT * 512;
        const unsigned short* FyHp = wsu + FYH_U + (size_t)b * NOUT * 512;
        const unsigned short* FyLp = wsu + FYL_U + (size_t)b * NOUT * 512;

        const float* xlane = Xp + (size_t)(16 * wv + l15) * W_ + quad * 8;

        const int srow0 = t >> 3;              // 0..31
        const int sc8 = (t & 7) * 8;           // 0,8,..56

        // prologue: stage Fx tile 0
        {
            uint4 h0 = *(const uint4*)(FxHp + (size_t)srow0 * 512 + sc8);
            uint4 l0 = *(const uint4*)(FxLp + (size_t)srow0 * 512 + sc8);
            uint4 h1 = *(const uint4*)(FxHp + (size_t)(srow0 + 32) * 512 + sc8);
            uint4 l1 = *(const uint4*)(FxLp + (size_t)(srow0 + 32) * 512 + sc8);
            *(uint4*)&Fh[srow0 * PITCH + sc8] = h0;
            *(uint4*)&Fl[srow0 * PITCH + sc8] = l0;
            *(uint4*)&Fh[(srow0 + 32) * PITCH + sc8] = h1;
            *(uint4*)&Fl[(srow0 + 32) * PITCH + sc8] = l1;
        }
        __syncthreads();

        f32x4 acc[4] = {};

        #pragma unroll
        for (int wt = 0; wt < 8; wt++) {
            unsigned short* curH = (wt & 1) ? Xh : Fh;
            unsigned short* curL = (wt & 1) ? Xl : Fl;
            unsigned short* nxtH = (wt & 1) ? Fh : Xh;
            unsigned short* nxtL = (wt & 1) ? Fl : Xl;

            uint4 nh0, nl0, nh1, nl1;
            if (wt < 7) {
                const int wb = (wt + 1) * KC;
                nh0 = *(const uint4*)(FxHp + (size_t)srow0 * 512 + wb + sc8);
                nl0 = *(const uint4*)(FxLp + (size_t)srow0 * 512 + wb + sc8);
                nh1 = *(const uint4*)(FxHp + (size_t)(srow0 + 32) * 512 + wb + sc8);
                nl1 = *(const uint4*)(FxLp + (size_t)(srow0 + 32) * 512 + wb + sc8);
            }

            #pragma unroll
            for (int ks = 0; ks < 2; ks++) {
                const float* xp = xlane + wt * KC + ks * 32;
                float4 x0 = *(const float4*)(xp);
                float4 x1 = *(const float4*)(xp + 4);
                BF8U ah, al;
                ah.u.x = cvt_pk_bf16(x0.x, x0.y);
                ah.u.y = cvt_pk_bf16(x0.z, x0.w);
                ah.u.z = cvt_pk_bf16(x1.x, x1.y);
                ah.u.w = cvt_pk_bf16(x1.z, x1.w);
                al.u.x = cvt_pk_bf16(x0.x - __uint_as_float(ah.u.x << 16),
                                     x0.y - __uint_as_float(ah.u.x & 0xffff0000u));
                al.u.y = cvt_pk_bf16(x0.z - __uint_as_float(ah.u.y << 16),
                                     x0.w - __uint_as_float(ah.u.y & 0xffff0000u));
                al.u.z = cvt_pk_bf16(x1.x - __uint_as_float(ah.u.z << 16),
                                     x1.y - __uint_as_float(ah.u.z & 0xffff0000u));
                al.u.w = cvt_pk_bf16(x1.z - __uint_as_float(ah.u.w << 16),
                                     x1.w - __uint_as_float(ah.u.w & 0xffff0000u));

                const int ko = ks * 32 + quad * 8;
                #pragma unroll
                for (int mt = 0; mt < 4; mt++) {
                    bf16x8 bh = *(const bf16x8*)&curH[(16 * mt + l15) * PITCH + ko];
                    bf16x8 bl2 = *(const bf16x8*)&curL[(16 * mt + l15) * PITCH + ko];
                    acc[mt] = __builtin_amdgcn_mfma_f32_16x16x32_bf16(ah.v, bh, acc[mt], 0, 0, 0);
                    acc[mt] = __builtin_amdgcn_mfma_f32_16x16x32_bf16(al.v, bh, acc[mt], 0, 0, 0);
                    acc[mt] = __builtin_amdgcn_mfma_f32_16x16x32_bf16(ah.v, bl2, acc[mt], 0, 0, 0);
                }
            }

            if (wt < 7) {
                *(uint4*)&nxtH[srow0 * PITCH + sc8] = nh0;
                *(uint4*)&nxtL[srow0 * PITCH + sc8] = nl0;
                *(uint4*)&nxtH[(srow0 + 32) * PITCH + sc8] = nh1;
                *(uint4*)&nxtL[(srow0 + 32) * PITCH + sc8] = nl1;
            }
            __syncthreads();
        }

        // write G transposed as hi/lo into Xh/Xl: Gt[m][h]
        #pragma unroll
        for (int mt = 0; mt < 4; mt++) {
            float g0 = acc[mt][0], g1 = acc[mt][1], g2 = acc[mt][2], g3 = acc[mt][3];
            unsigned int h01 = cvt_pk_bf16(g0, g1);
            unsigned int h23 = cvt_pk_bf16(g2, g3);
            float r0 = __uint_as_float(h01 << 16);
            float r1 = __uint_as_float(h01 & 0xffff0000u);
            float r2 = __uint_as_float(h23 << 16);
            float r3 = __uint_as_float(h23 & 0xffff0000u);
            unsigned int l01 = cvt_pk_bf16(g0 - r0, g1 - r1);
            unsigned int l23 = cvt_pk_bf16(g2 - r2, g3 - r3);
            int m = 16 * mt + l15;
            int h = 16 * wv + quad * 4;
            int o = m * PITCH + h;
            *(uint2*)&Xh[o] = make_uint2(h01, h23);
            *(uint2*)&Xl[o] = make_uint2(l01, l23);
        }

        // stage Fy chunk
        {
            uint4 h0 = *(const uint4*)(FyHp + (size_t)srow0 * 512 + hbase + sc8);
            uint4 l0 = *(const uint4*)(FyLp + (size_t)srow0 * 512 + hbase + sc8);
            uint4 h1 = *(const uint4*)(FyHp + (size_t)(srow0 + 32) * 512 + hbase + sc8);
            uint4 l1 = *(const uint4*)(FyLp + (size_t)(srow0 + 32) * 512 + hbase + sc8);
            *(uint4*)&Fh[srow0 * PITCH + sc8] = h0;
            *(uint4*)&Fl[srow0 * PITCH + sc8] = l0;
            *(uint4*)&Fh[(srow0 + 32) * PITCH + sc8] = h1;
            *(uint4*)&Fl[(srow0 + 32) * PITCH + sc8] = l1;
        }
        __syncthreads();

        // GEMM2
        f32x4 p[4] = {};
        #pragma unroll
        for (int ks = 0; ks < 2; ks++) {
            const int ko = ks * 32 + quad * 8;
            bf16x8 yh = *(const bf16x8*)&Fh[(16 * wv + l15) * PITCH + ko];
            bf16x8 yl = *(const bf16x8*)&Fl[(16 * wv + l15) * PITCH + ko];
            #pragma unroll
            for (int mt = 0; mt < 4; mt++) {
                bf16x8 gh = *(const bf16x8*)&Xh[(16 * mt + l15) * PITCH + ko];
                bf16x8 gl = *(const bf16x8*)&Xl[(16 * mt + l15) * PITCH + ko];
                p[mt] = __builtin_amdgcn_mfma_f32_16x16x32_bf16(yh, gh, p[mt], 0, 0, 0);
                p[mt] = __builtin_amdgcn_mfma_f32_16x16x32_bf16(yl, gh, p[mt], 0, 0, 0);
                p[mt] = __builtin_amdgcn_mfma_f32_16x16x32_bf16(yh, gl, p[mt], 0, 0, 0);
            }
        }

        const float gamma = ws[PF_OFF + b * 8 + 4];
        float* outp = out + (size_t)bc * (NOUT * NOUT);
        #pragma unroll
        for (int mt = 0; mt < 4; mt++)
            #pragma unroll
            for (int r = 0; r < 4; r++) {
                int n = 16 * wv + quad * 4 + r;
                int m = 16 * mt + l15;
                atomicAdd(&outp[n * NOUT + m], gamma * p[mt][r]);
            }
    }
}

extern "C" void kernel_launch(void* const* d_in, const int* in_sizes, int n_in,
                              void* d_out, int out_size, void* d_ws, size_t ws_size,
                              hipStream_t stream) {
    const float* X  = (const float*)d_in[0];
    const float* Wl = (const float*)d_in[1];
    const float* bl = (const float*)d_in[2];
    float* out = (float*)d_out;
    float* ws  = (float*)d_ws;

    // zero the grid-barrier counters (captured into the graph -> runs every replay)
    hipMemsetAsync((char*)ws + BAR_OFF * sizeof(float), 0, 2 * sizeof(unsigned), stream);

    k_fused<<<dim3(GRID), dim3(256), 0, stream>>>(X, Wl, bl, ws, out);
}

// Round 7
// 444.445 us; speedup vs baseline: 1.1564x; 1.1564x over previous
//
#include <hip/hip_runtime.h>
#include <math.h>

#define B_ 32
#define C_ 3
#define H_ 512
#define W_ 512
#define NOUT 64
#define FAN (C_*H_*W_)          // 786432

#define CHUNKS 192
#define CELEMS (FAN / CHUNKS)   // 4096
#define GRID 768                // = 192 chunks x 4 bgroups = 8 hc x 96 bc

// workspace layout (floats):
//   [0, 30720): per-chunk locnet partials P[chunk][b][j] (stride 160)
//   [PF_OFF, +256): pf[b][8] = {p0..p3 biased, gamma, pad}
//   [BAR_OFF, +2): grid-barrier {cnt, gen} (uint), zeroed by captured memset
//   ushort images at ws + PFLOATS floats: FxH, FxL, FyH, FyL (1,048,576 ushorts each)
#define PPART_STRIDE 160
#define PF_OFF (CHUNKS * PPART_STRIDE)   // 30720
#define BAR_OFF 31000
#define PFLOATS 32768
#define FXH_U 0
#define FXL_U 1048576
#define FYH_U 2097152
#define FYL_U 3145728

typedef __bf16 bf16x8 __attribute__((ext_vector_type(8)));
typedef float f32x4 __attribute__((ext_vector_type(4)));

__device__ __forceinline__ unsigned short f2bf(float f) {
    unsigned int u = __float_as_uint(f);
    u = (u + 0x7FFFu + ((u >> 16) & 1u)) >> 16;
    return (unsigned short)u;
}
__device__ __forceinline__ float bf2f(unsigned short h) {
    return __uint_as_float(((unsigned int)h) << 16);
}
__device__ __forceinline__ unsigned int cvt_pk_bf16(float lo, float hi) {
    unsigned int r;
    asm("v_cvt_pk_bf16_f32 %0, %1, %2" : "=v"(r) : "v"(lo), "v"(hi));
    return r;
}

union BF8U { uint4 u; bf16x8 v; };

// sense-reversing grid barrier; all 768 blocks resident by construction
// (LDS 36.9KB -> 4 blk/CU; launch_bounds(256,4) -> VGPR<=128 -> 16 waves/CU; 1024>=768).
// Spin uses RELAXED loads + s_sleep backoff: no per-iteration cache maintenance
// (R6's ACQUIRE spin invalidated the CU-shared L1 every iteration -> 408us idle).
__device__ __forceinline__ void grid_barrier(unsigned* bar, int t) {
    __syncthreads();
    if (t == 0) {
        __threadfence();   // release: make this block's writes device-visible
        unsigned g = __hip_atomic_load(&bar[1], __ATOMIC_RELAXED, __HIP_MEMORY_SCOPE_AGENT);
        unsigned arrived = __hip_atomic_fetch_add(&bar[0], 1u, __ATOMIC_RELAXED,
                                                  __HIP_MEMORY_SCOPE_AGENT) + 1u;
        if (arrived == (unsigned)GRID) {
            __hip_atomic_store(&bar[0], 0u, __ATOMIC_RELAXED, __HIP_MEMORY_SCOPE_AGENT);
            __hip_atomic_store(&bar[1], g + 1u, __ATOMIC_RELAXED, __HIP_MEMORY_SCOPE_AGENT);
        } else {
            long cap = 0;
            while (__hip_atomic_load(&bar[1], __ATOMIC_RELAXED,
                                     __HIP_MEMORY_SCOPE_AGENT) == g) {
                __builtin_amdgcn_s_sleep(8);      // ~512 cycles backoff
                if (++cap > (1L << 20)) break;    // failsafe: fail, don't hang
            }
        }
        __threadfence();   // acquire: invalidate so we see others' writes
    }
    __syncthreads();
}

#define KC 64
#define PITCH 72            // ushorts per LDS row
#define TSZ (64 * PITCH)    // 4608 ushorts per array

__global__ __launch_bounds__(256, 4) void k_fused(const float* __restrict__ X,
                                                  const float* __restrict__ Wl,
                                                  const float* __restrict__ bl,
                                                  float* __restrict__ ws,
                                                  float* __restrict__ out) {
    const int bid = blockIdx.x;
    const int t = threadIdx.x;
    const int lane = t & 63;
    const int wave = t >> 6;
    unsigned* bar = (unsigned*)(ws + BAR_OFF);

    __shared__ __align__(16) unsigned short lds[4 * TSZ];   // 36864 B
    __shared__ float sred[4][40];
    __shared__ float sredB[4];
    __shared__ float stot;

    // ================= Phase A: locnet partials (2 passes of 4 batches) =================
    // Split 8 batches -> 2x4 to keep live regs ~55 (acc[4][5]=20): avoids the
    // R6 spill at the VGPR=64 allocation. W slice re-read on pass 2 is L2-hot.
    {
        const int chunk = bid >> 2;        // 0..191
        const int b0 = (bid & 3) * 8;      // 0,8,16,24
        const size_t base = (size_t)chunk * CELEMS;

        #pragma unroll 1
        for (int half = 0; half < 2; half++) {
            const int bh = b0 + half * 4;
            float acc[4][5] = {};

            for (int k = t; k < CELEMS / 4; k += 256) {   // 4 iterations
                const size_t i0 = base + (size_t)k * 4;
                const float4* W4 = (const float4*)(Wl + i0 * 5);
                float4 w0 = W4[0], w1 = W4[1], w2 = W4[2], w3 = W4[3], w4 = W4[4];
                float wv[20] = {w0.x, w0.y, w0.z, w0.w,
                                w1.x, w1.y, w1.z, w1.w,
                                w2.x, w2.y, w2.z, w2.w,
                                w3.x, w3.y, w3.z, w3.w,
                                w4.x, w4.y, w4.z, w4.w};
                #pragma unroll
                for (int bb = 0; bb < 4; bb++) {
                    float4 x = *(const float4*)(X + (size_t)(bh + bb) * FAN + i0);
                    float xv[4] = {x.x, x.y, x.z, x.w};
                    #pragma unroll
                    for (int e = 0; e < 4; e++)
                        #pragma unroll
                        for (int j = 0; j < 5; j++)
                            acc[bb][j] += xv[e] * wv[e * 5 + j];
                }
            }

            #pragma unroll
            for (int off = 32; off > 0; off >>= 1)
                #pragma unroll
                for (int bb = 0; bb < 4; bb++)
                    #pragma unroll
                    for (int j = 0; j < 5; j++)
                        acc[bb][j] += __shfl_down(acc[bb][j], off);

            if (lane == 0) {
                #pragma unroll
                for (int bb = 0; bb < 4; bb++)
                    #pragma unroll
                    for (int j = 0; j < 5; j++)
                        sred[wave][bb * 5 + j] = acc[bb][j];
            }
            __syncthreads();
            if (t < 20) {
                float s = sred[0][t] + sred[1][t] + sred[2][t] + sred[3][t];
                ws[(size_t)chunk * PPART_STRIDE + bh * 5 + t] = s;
            }
            __syncthreads();
        }
    }
    grid_barrier(bar, t);

    // ================= Phase B0: reduce partials -> pf[b][.] =================
    if (bid < B_) {
        const int b = bid;
        float pj[5] = {0.f, 0.f, 0.f, 0.f, 0.f};
        if (t < CHUNKS) {
            const float* pr = ws + (size_t)t * PPART_STRIDE + b * 5;
            #pragma unroll
            for (int j = 0; j < 5; j++) pj[j] = pr[j];
        }
        #pragma unroll
        for (int off = 32; off > 0; off >>= 1)
            #pragma unroll
            for (int j = 0; j < 5; j++) pj[j] += __shfl_down(pj[j], off);
        if (lane == 0) {
            #pragma unroll
            for (int j = 0; j < 5; j++) sred[wave][j] = pj[j];
        }
        __syncthreads();
        if (t < 5) {
            float v = sred[0][t] + sred[1][t] + sred[2][t] + sred[3][t] + bl[t];
            ws[PF_OFF + b * 8 + t] = (t == 4) ? expf(v) : v;
        }
    }
    grid_barrier(bar, t);

    // ================= Phase B: filters (bf16 hi/lo) + zero out =================
    for (int u = bid; u < 2 * B_ * NOUT; u += GRID) {   // 4096 units
        const int which = u >> 11;
        const int b = (u >> 6) & 31;
        const int n = u & 63;

        if (t < 24)
            ((float4*)out)[(size_t)u * 24 + t] = make_float4(0.f, 0.f, 0.f, 0.f);

        const float p0 = ws[PF_OFF + b * 8 + 0];
        const float p1 = ws[PF_OFF + b * 8 + 1];
        const float p2 = ws[PF_OFF + b * 8 + 2];
        const float p3 = ws[PF_OFF + b * 8 + 3];

        const float g = (which == 0) ? 32.f * (p0 + 1.f) : 32.f * (p1 + 1.f);
        const float sigma2 = expf(p2);
        const float inv2s = 0.5f / sigma2;
        const float delta = expf(p3) * (511.0f / 63.0f);
        const float mean = g + delta * ((float)n - 32.5f);

        float d0 = (float)(2 * t) - mean;
        float f0 = expf(-d0 * d0 * inv2s);
        float d1 = (float)(2 * t + 1) - mean;
        float f1 = expf(-d1 * d1 * inv2s);

        float s = f0 + f1;
        #pragma unroll
        for (int off = 32; off > 0; off >>= 1) s += __shfl_down(s, off);
        if (lane == 0) sredB[wave] = s;
        __syncthreads();
        if (t == 0) stot = sredB[0] + sredB[1] + sredB[2] + sredB[3] + 1e-4f;
        __syncthreads();
        const float scale = 1.0f / stot;

        unsigned short* wsu = (unsigned short*)(ws + PFLOATS);
        unsigned int* dstH = (unsigned int*)(wsu + (which ? FYH_U : FXH_U) + ((size_t)b * NOUT + n) * 512);
        unsigned int* dstL = (unsigned int*)(wsu + (which ? FYL_U : FXL_U) + ((size_t)b * NOUT + n) * 512);

        float v0 = f0 * scale;
        float v1 = f1 * scale;
        unsigned short h0 = f2bf(v0);
        unsigned short h1 = f2bf(v1);
        unsigned short l0 = f2bf(v0 - bf2f(h0));
        unsigned short l1 = f2bf(v1 - bf2f(h1));
        dstH[t] = (unsigned int)h0 | ((unsigned int)h1 << 16);
        dstL[t] = (unsigned int)l0 | ((unsigned int)l1 << 16);
        __syncthreads();
    }
    grid_barrier(bar, t);

    // ================= Phase C: MFMA glimpse (R3 structure) =================
    {
        const int hc = bid & 7;       // 0..7
        const int bc = bid >> 3;      // 0..95
        const int b = bc / 3;
        const int wv = wave;
        const int l15 = lane & 15;
        const int quad = lane >> 4;
        const int hbase = hc * 64;

        unsigned short* Xh = lds;
        unsigned short* Xl = lds + TSZ;
        unsigned short* Fh = lds + 2 * TSZ;
        unsigned short* Fl = lds + 3 * TSZ;

        const float* Xp = X + (size_t)bc * (H_ * W_) + (size_t)hbase * W_;
        const unsigned short* wsu = (const unsigned short*)(ws + PFLOATS);
        const unsigned short* FxHp = wsu + FXH_U + (size_t)b * NOUT * 512;
        const unsigned short* FxLp = wsu + FXL_U + (size_t)b * NOUT * 512;
        const unsigned short* FyHp = wsu + FYH_U + (size_t)b * NOUT * 512;
        const unsigned short* FyLp = wsu + FYL_U + (size_t)b * NOUT * 512;

        const float* xlane = Xp + (size_t)(16 * wv + l15) * W_ + quad * 8;

        const int srow0 = t >> 3;              // 0..31
        const int sc8 = (t & 7) * 8;           // 0,8,..56

        // prologue: stage Fx tile 0
        {
            uint4 h0 = *(const uint4*)(FxHp + (size_t)srow0 * 512 + sc8);
            uint4 l0 = *(const uint4*)(FxLp + (size_t)srow0 * 512 + sc8);
            uint4 h1 = *(const uint4*)(FxHp + (size_t)(srow0 + 32) * 512 + sc8);
            uint4 l1 = *(const uint4*)(FxLp + (size_t)(srow0 + 32) * 512 + sc8);
            *(uint4*)&Fh[srow0 * PITCH + sc8] = h0;
            *(uint4*)&Fl[srow0 * PITCH + sc8] = l0;
            *(uint4*)&Fh[(srow0 + 32) * PITCH + sc8] = h1;
            *(uint4*)&Fl[(srow0 + 32) * PITCH + sc8] = l1;
        }
        __syncthreads();

        f32x4 acc[4] = {};

        #pragma unroll
        for (int wt = 0; wt < 8; wt++) {
            unsigned short* curH = (wt & 1) ? Xh : Fh;
            unsigned short* curL = (wt & 1) ? Xl : Fl;
            unsigned short* nxtH = (wt & 1) ? Fh : Xh;
            unsigned short* nxtL = (wt & 1) ? Fl : Xl;

            uint4 nh0, nl0, nh1, nl1;
            if (wt < 7) {
                const int wb = (wt + 1) * KC;
                nh0 = *(const uint4*)(FxHp + (size_t)srow0 * 512 + wb + sc8);
                nl0 = *(const uint4*)(FxLp + (size_t)srow0 * 512 + wb + sc8);
                nh1 = *(const uint4*)(FxHp + (size_t)(srow0 + 32) * 512 + wb + sc8);
                nl1 = *(const uint4*)(FxLp + (size_t)(srow0 + 32) * 512 + wb + sc8);
            }

            #pragma unroll
            for (int ks = 0; ks < 2; ks++) {
                const float* xp = xlane + wt * KC + ks * 32;
                float4 x0 = *(const float4*)(xp);
                float4 x1 = *(const float4*)(xp + 4);
                BF8U ah, al;
                ah.u.x = cvt_pk_bf16(x0.x, x0.y);
                ah.u.y = cvt_pk_bf16(x0.z, x0.w);
                ah.u.z = cvt_pk_bf16(x1.x, x1.y);
                ah.u.w = cvt_pk_bf16(x1.z, x1.w);
                al.u.x = cvt_pk_bf16(x0.x - __uint_as_float(ah.u.x << 16),
                                     x0.y - __uint_as_float(ah.u.x & 0xffff0000u));
                al.u.y = cvt_pk_bf16(x0.z - __uint_as_float(ah.u.y << 16),
                                     x0.w - __uint_as_float(ah.u.y & 0xffff0000u));
                al.u.z = cvt_pk_bf16(x1.x - __uint_as_float(ah.u.z << 16),
                                     x1.y - __uint_as_float(ah.u.z & 0xffff0000u));
                al.u.w = cvt_pk_bf16(x1.z - __uint_as_float(ah.u.w << 16),
                                     x1.w - __uint_as_float(ah.u.w & 0xffff0000u));

                const int ko = ks * 32 + quad * 8;
                #pragma unroll
                for (int mt = 0; mt < 4; mt++) {
                    bf16x8 bh = *(const bf16x8*)&curH[(16 * mt + l15) * PITCH + ko];
                    bf16x8 bl2 = *(const bf16x8*)&curL[(16 * mt + l15) * PITCH + ko];
                    acc[mt] = __builtin_amdgcn_mfma_f32_16x16x32_bf16(ah.v, bh, acc[mt], 0, 0, 0);
                    acc[mt] = __builtin_amdgcn_mfma_f32_16x16x32_bf16(al.v, bh, acc[mt], 0, 0, 0);
                    acc[mt] = __builtin_amdgcn_mfma_f32_16x16x32_bf16(ah.v, bl2, acc[mt], 0, 0, 0);
                }
            }

            if (wt < 7) {
                *(uint4*)&nxtH[srow0 * PITCH + sc8] = nh0;
                *(uint4*)&nxtL[srow0 * PITCH + sc8] = nl0;
                *(uint4*)&nxtH[(srow0 + 32) * PITCH + sc8] = nh1;
                *(uint4*)&nxtL[(srow0 + 32) * PITCH + sc8] = nl1;
            }
            __syncthreads();
        }

        // write G transposed as hi/lo into Xh/Xl: Gt[m][h]
        #pragma unroll
        for (int mt = 0; mt < 4; mt++) {
            float g0 = acc[mt][0], g1 = acc[mt][1], g2 = acc[mt][2], g3 = acc[mt][3];
            unsigned int h01 = cvt_pk_bf16(g0, g1);
            unsigned int h23 = cvt_pk_bf16(g2, g3);
            float r0 = __uint_as_float(h01 << 16);
            float r1 = __uint_as_float(h01 & 0xffff0000u);
            float r2 = __uint_as_float(h23 << 16);
            float r3 = __uint_as_float(h23 & 0xffff0000u);
            unsigned int l01 = cvt_pk_bf16(g0 - r0, g1 - r1);
            unsigned int l23 = cvt_pk_bf16(g2 - r2, g3 - r3);
            int m = 16 * mt + l15;
            int h = 16 * wv + quad * 4;
            int o = m * PITCH + h;
            *(uint2*)&Xh[o] = make_uint2(h01, h23);
            *(uint2*)&Xl[o] = make_uint2(l01, l23);
        }

        // stage Fy chunk
        {
            uint4 h0 = *(const uint4*)(FyHp + (size_t)srow0 * 512 + hbase + sc8);
            uint4 l0 = *(const uint4*)(FyLp + (size_t)srow0 * 512 + hbase + sc8);
            uint4 h1 = *(const uint4*)(FyHp + (size_t)(srow0 + 32) * 512 + hbase + sc8);
            uint4 l1 = *(const uint4*)(FyLp + (size_t)(srow0 + 32) * 512 + hbase + sc8);
            *(uint4*)&Fh[srow0 * PITCH + sc8] = h0;
            *(uint4*)&Fl[srow0 * PITCH + sc8] = l0;
            *(uint4*)&Fh[(srow0 + 32) * PITCH + sc8] = h1;
            *(uint4*)&Fl[(srow0 + 32) * PITCH + sc8] = l1;
        }
        __syncthreads();

        // GEMM2
        f32x4 p[4] = {};
        #pragma unroll
        for (int ks = 0; ks < 2; ks++) {
            const int ko = ks * 32 + quad * 8;
            bf16x8 yh = *(const bf16x8*)&Fh[(16 * wv + l15) * PITCH + ko];
            bf16x8 yl = *(const bf16x8*)&Fl[(16 * wv + l15) * PITCH + ko];
            #pragma unroll
            for (int mt = 0; mt < 4; mt++) {
                bf16x8 gh = *(const bf16x8*)&Xh[(16 * mt + l15) * PITCH + ko];
                bf16x8 gl = *(const bf16x8*)&Xl[(16 * mt + l15) * PITCH + ko];
                p[mt] = __builtin_amdgcn_mfma_f32_16x16x32_bf16(yh, gh, p[mt], 0, 0, 0);
                p[mt] = __builtin_amdgcn_mfma_f32_16x16x32_bf16(yl, gh, p[mt], 0, 0, 0);
                p[mt] = __builtin_amdgcn_mfma_f32_16x16x32_bf16(yh, gl, p[mt], 0, 0, 0);
            }
        }

        const float gamma = ws[PF_OFF + b * 8 + 4];
        float* outp = out + (size_t)bc * (NOUT * NOUT);
        #pragma unroll
        for (int mt = 0; mt < 4; mt++)
            #pragma unroll
            for (int r = 0; r < 4; r++) {
                int n = 16 * wv + quad * 4 + r;
                int m = 16 * mt + l15;
                atomicAdd(&outp[n * NOUT + m], gamma * p[mt][r]);
            }
    }
}

extern "C" void kernel_launch(void* const* d_in, const int* in_sizes, int n_in,
                              void* d_out, int out_size, void* d_ws, size_t ws_size,
                              hipStream_t stream) {
    const float* X  = (const float*)d_in[0];
    const float* Wl = (const float*)d_in[1];
    const float* bl = (const float*)d_in[2];
    float* out = (float*)d_out;
    float* ws  = (float*)d_ws;

    // zero the grid-barrier counters (captured into the graph -> runs every replay)
    hipMemsetAsync((char*)ws + BAR_OFF * sizeof(float), 0, 2 * sizeof(unsigned), stream);

    k_fused<<<dim3(GRID), dim3(256), 0, stream>>>(X, Wl, bl, ws, out);
}

// Round 8
// 210.323 us; speedup vs baseline: 2.4436x; 2.1132x over previous
//
#include <hip/hip_runtime.h>
#include <math.h>

#define B_ 32
#define C_ 3
#define H_ 512
#define W_ 512
#define NOUT 64
#define FAN (C_*H_*W_)          // 786432

// locnet decomposition: 1536 blocks (6/CU), 2-iteration body (compiler fully
// unrolls -> ~2x in-flight loads/thread) for HBM latency hiding
#define CHUNKS 384
#define CELEMS (FAN / CHUNKS)   // 2048
#define BGROUPS 4               // 8 batches per block

// workspace layout:
//   floats [0, 384*160): per-chunk locnet partials P[chunk][b][j]
//   floats [GAMMA_OFF, +32): gamma[b] (written by k_filters)
//   then ushort images (base = ws + PFLOATS floats):
//     FxH [32][64][512], FxL, FyH, FyL  (1,048,576 ushorts = 2MB each)
#define PPART_STRIDE 160
#define GAMMA_OFF (CHUNKS * PPART_STRIDE)   // 61440
#define PFLOATS 65536
#define FXH_U 0
#define FXL_U 1048576
#define FYH_U 2097152
#define FYL_U 3145728

typedef __bf16 bf16x8 __attribute__((ext_vector_type(8)));
typedef float f32x4 __attribute__((ext_vector_type(4)));

// round-to-nearest-even fp32 -> bf16 (as ushort) — integer emulation (exact RNE)
__device__ __forceinline__ unsigned short f2bf(float f) {
    unsigned int u = __float_as_uint(f);
    u = (u + 0x7FFFu + ((u >> 16) & 1u)) >> 16;
    return (unsigned short)u;
}
__device__ __forceinline__ float bf2f(unsigned short h) {
    return __uint_as_float(((unsigned int)h) << 16);
}
// packed fp32x2 -> bf16x2 in one VALU op (hw RNE; identical results to f2bf)
__device__ __forceinline__ unsigned int cvt_pk_bf16(float lo, float hi) {
    unsigned int r;
    asm("v_cvt_pk_bf16_f32 %0, %1, %2" : "=v"(r) : "v"(lo), "v"(hi));
    return r;
}

union BF8U { uint4 u; bf16x8 v; };

// ---------------- kernel 1: partial p[b,j] = sum_i X[b,i] * W_loc[i,j] ----------------
__global__ __launch_bounds__(256) void k_locnet(const float* __restrict__ X,
                                                const float* __restrict__ Wl,
                                                float* __restrict__ ws) {
    const int chunk = blockIdx.x;      // 0..CHUNKS-1
    const int b0 = blockIdx.y * 8;     // 0,8,16,24
    const int t = threadIdx.x;

    float acc[8][5] = {};
    const size_t base = (size_t)chunk * CELEMS;

    for (int k = t; k < CELEMS / 4; k += 256) {   // 2 iterations (fully unrolled)
        const size_t i0 = base + (size_t)k * 4;
        const float4* W4 = (const float4*)(Wl + i0 * 5);
        float4 w0 = W4[0], w1 = W4[1], w2 = W4[2], w3 = W4[3], w4 = W4[4];
        float wv[20] = {w0.x, w0.y, w0.z, w0.w,
                        w1.x, w1.y, w1.z, w1.w,
                        w2.x, w2.y, w2.z, w2.w,
                        w3.x, w3.y, w3.z, w3.w,
                        w4.x, w4.y, w4.z, w4.w};
        #pragma unroll
        for (int bb = 0; bb < 8; bb++) {
            float4 x = *(const float4*)(X + (size_t)(b0 + bb) * FAN + i0);
            float xv[4] = {x.x, x.y, x.z, x.w};
            #pragma unroll
            for (int e = 0; e < 4; e++)
                #pragma unroll
                for (int j = 0; j < 5; j++)
                    acc[bb][j] += xv[e] * wv[e * 5 + j];
        }
    }

    #pragma unroll
    for (int off = 32; off > 0; off >>= 1)
        #pragma unroll
        for (int bb = 0; bb < 8; bb++)
            #pragma unroll
            for (int j = 0; j < 5; j++)
                acc[bb][j] += __shfl_down(acc[bb][j], off);

    __shared__ float sred[4][40];
    const int wave = t >> 6, lane = t & 63;
    if (lane == 0) {
        #pragma unroll
        for (int bb = 0; bb < 8; bb++)
            #pragma unroll
            for (int j = 0; j < 5; j++)
                sred[wave][bb * 5 + j] = acc[bb][j];
    }
    __syncthreads();
    if (t < 40) {
        float s = sred[0][t] + sred[1][t] + sred[2][t] + sred[3][t];
        ws[(size_t)chunk * PPART_STRIDE + b0 * 5 + t] = s;
    }
}

// ---------------- kernel 2: reduce p, build normalized filters (bf16 hi/lo), zero out ----------------
__global__ __launch_bounds__(256) void k_filters(const float* __restrict__ bl,
                                                 float* __restrict__ ws,
                                                 float* __restrict__ out) {
    const int n = blockIdx.x;
    const int b = blockIdx.y;
    const int which = blockIdx.z;
    const int t = threadIdx.x;

    // zero a 96-float slice of out (replaces a 1.5MB memset dispatch)
    {
        const int bid = blockIdx.x + NOUT * (blockIdx.y + B_ * blockIdx.z);  // 0..4095
        if (t < 24) {
            ((float4*)out)[(size_t)bid * 24 + t] = make_float4(0.f, 0.f, 0.f, 0.f);
        }
    }

    // reduce locnet partials: p[j] = bl[j] + sum_{chunk<384} ws[chunk*160 + b*5 + j]
    float pj[5];
    {
        const float* pr = ws + (size_t)t * PPART_STRIDE + b * 5;   // t < 256 <= CHUNKS
        #pragma unroll
        for (int j = 0; j < 5; j++) pj[j] = pr[j];
        if (t < CHUNKS - 256) {
            const float* pr2 = ws + (size_t)(t + 256) * PPART_STRIDE + b * 5;
            #pragma unroll
            for (int j = 0; j < 5; j++) pj[j] += pr2[j];
        }
    }
    #pragma unroll
    for (int off = 32; off > 0; off >>= 1)
        #pragma unroll
        for (int j = 0; j < 5; j++) pj[j] += __shfl_down(pj[j], off);

    __shared__ float spart[4][5];
    __shared__ float pfin[5];
    const int wave = t >> 6, lane = t & 63;
    if (lane == 0) {
        #pragma unroll
        for (int j = 0; j < 5; j++) spart[wave][j] = pj[j];
    }
    __syncthreads();
    if (t < 5) pfin[t] = spart[0][t] + spart[1][t] + spart[2][t] + spart[3][t] + bl[t];
    __syncthreads();

    const float p0 = pfin[0], p1 = pfin[1], p2 = pfin[2], p3 = pfin[3];
    if (which == 0 && n == 0 && t == 0) ws[GAMMA_OFF + b] = expf(pfin[4]);

    const float g = (which == 0) ? 32.f * (p0 + 1.f) : 32.f * (p1 + 1.f);
    const float sigma2 = expf(p2);
    const float inv2s = 0.5f / sigma2;
    const float delta = expf(p3) * (511.0f / 63.0f);
    const float mean = g + delta * ((float)n - 32.5f);

    // thread t handles elements 2t, 2t+1 (packed 4B stores)
    float d0 = (float)(2 * t) - mean;
    float f0 = expf(-d0 * d0 * inv2s);
    float d1 = (float)(2 * t + 1) - mean;
    float f1 = expf(-d1 * d1 * inv2s);

    float s = f0 + f1;
    #pragma unroll
    for (int off = 32; off > 0; off >>= 1) s += __shfl_down(s, off);
    __shared__ float sred[4];
    __shared__ float stot;
    if (lane == 0) sred[wave] = s;
    __syncthreads();
    if (t == 0) stot = sred[0] + sred[1] + sred[2] + sred[3] + 1e-4f;
    __syncthreads();
    const float scale = 1.0f / stot;

    unsigned short* wsu = (unsigned short*)(ws + PFLOATS);
    unsigned int* dstH = (unsigned int*)(wsu + (which ? FYH_U : FXH_U) + ((size_t)b * NOUT + n) * 512);
    unsigned int* dstL = (unsigned int*)(wsu + (which ? FYL_U : FXL_U) + ((size_t)b * NOUT + n) * 512);

    float v0 = f0 * scale;
    float v1 = f1 * scale;
    unsigned short h0 = f2bf(v0);
    unsigned short h1 = f2bf(v1);
    unsigned short l0 = f2bf(v0 - bf2f(h0));
    unsigned short l1 = f2bf(v1 - bf2f(h1));
    dstH[t] = (unsigned int)h0 | ((unsigned int)h1 << 16);
    dstL[t] = (unsigned int)l0 | ((unsigned int)l1 << 16);
}

// ---------------- kernel 3: MFMA glimpse (R3 structure, best verified) ----------------
// out[b,c] += gamma * Fy_chunk @ (X_chunk @ Fx^T), split-bf16 (hi+lo) MFMA.
// grid (8 hc, 96 bc), 256 threads = 4 waves.
// GEMM1: A (X rows) loaded DIRECT global->fragment (row = 16*wv + l15, k = quad*8)
//        — no X LDS staging. Fx chunks double-buffered in LDS: one barrier per
//        tile; next-tile filter loads issue before the MFMAs.
#define KC 64
#define PITCH 72            // ushorts per LDS row (16B-aligned rows, low-conflict)
#define TSZ (64 * PITCH)    // 4608 ushorts per array

__global__ __launch_bounds__(256) void k_glimpse(const float* __restrict__ X,
                                                 const float* __restrict__ ws,
                                                 float* __restrict__ out) {
    const int hc = blockIdx.x;   // 0..7
    const int bc = blockIdx.y;   // 0..95
    const int b = bc / 3;
    const int t = threadIdx.x;
    const int lane = t & 63;
    const int wv = t >> 6;       // 0..3
    const int l15 = lane & 15;
    const int quad = lane >> 4;  // 0..3
    const int hbase = hc * 64;

    __shared__ __align__(16) unsigned short lds[4 * TSZ];   // 36864 B
    unsigned short* Xh = lds;             // odd-tile Fx hi -> later Gt hi
    unsigned short* Xl = lds + TSZ;       // odd-tile Fx lo -> later Gt lo
    unsigned short* Fh = lds + 2 * TSZ;   // even-tile Fx hi -> later Fy hi
    unsigned short* Fl = lds + 3 * TSZ;   // even-tile Fx lo -> later Fy lo

    const float* Xp = X + (size_t)bc * (H_ * W_) + (size_t)hbase * W_;
    const unsigned short* wsu = (const unsigned short*)(ws + PFLOATS);
    const unsigned short* FxHp = wsu + FXH_U + (size_t)b * NOUT * 512;
    const unsigned short* FxLp = wsu + FXL_U + (size_t)b * NOUT * 512;
    const unsigned short* FyHp = wsu + FYH_U + (size_t)b * NOUT * 512;
    const unsigned short* FyLp = wsu + FYL_U + (size_t)b * NOUT * 512;

    // per-lane X row pointer for direct A-fragment loads
    const float* xlane = Xp + (size_t)(16 * wv + l15) * W_ + quad * 8;

    // staging index mapping (Fx/Fy chunks): thread covers 2 rows x 16B
    const int srow0 = t >> 3;              // 0..31
    const int sc8 = (t & 7) * 8;           // 0,8,..56

    // ---- prologue: stage Fx tile 0 into Fh/Fl ----
    {
        uint4 h0 = *(const uint4*)(FxHp + (size_t)srow0 * 512 + sc8);
        uint4 l0 = *(const uint4*)(FxLp + (size_t)srow0 * 512 + sc8);
        uint4 h1 = *(const uint4*)(FxHp + (size_t)(srow0 + 32) * 512 + sc8);
        uint4 l1 = *(const uint4*)(FxLp + (size_t)(srow0 + 32) * 512 + sc8);
        *(uint4*)&Fh[srow0 * PITCH + sc8] = h0;
        *(uint4*)&Fl[srow0 * PITCH + sc8] = l0;
        *(uint4*)&Fh[(srow0 + 32) * PITCH + sc8] = h1;
        *(uint4*)&Fl[(srow0 + 32) * PITCH + sc8] = l1;
    }
    __syncthreads();

    f32x4 acc[4] = {};   // G: wave rows [16wv,+16), 4 m-tiles

    #pragma unroll
    for (int wt = 0; wt < 8; wt++) {
        unsigned short* curH = (wt & 1) ? Xh : Fh;
        unsigned short* curL = (wt & 1) ? Xl : Fl;
        unsigned short* nxtH = (wt & 1) ? Fh : Xh;
        unsigned short* nxtL = (wt & 1) ? Fl : Xl;

        // issue next-tile filter loads (latency hides under the MFMAs below)
        uint4 nh0, nl0, nh1, nl1;
        if (wt < 7) {
            const int wb = (wt + 1) * KC;
            nh0 = *(const uint4*)(FxHp + (size_t)srow0 * 512 + wb + sc8);
            nl0 = *(const uint4*)(FxLp + (size_t)srow0 * 512 + wb + sc8);
            nh1 = *(const uint4*)(FxHp + (size_t)(srow0 + 32) * 512 + wb + sc8);
            nl1 = *(const uint4*)(FxLp + (size_t)(srow0 + 32) * 512 + wb + sc8);
        }

        // ---- GEMM1 MFMAs on current tile; X loaded direct to fragments ----
        #pragma unroll
        for (int ks = 0; ks < 2; ks++) {
            const float* xp = xlane + wt * KC + ks * 32;
            float4 x0 = *(const float4*)(xp);
            float4 x1 = *(const float4*)(xp + 4);
            BF8U ah, al;
            ah.u.x = cvt_pk_bf16(x0.x, x0.y);
            ah.u.y = cvt_pk_bf16(x0.z, x0.w);
            ah.u.z = cvt_pk_bf16(x1.x, x1.y);
            ah.u.w = cvt_pk_bf16(x1.z, x1.w);
            al.u.x = cvt_pk_bf16(x0.x - __uint_as_float(ah.u.x << 16),
                                 x0.y - __uint_as_float(ah.u.x & 0xffff0000u));
            al.u.y = cvt_pk_bf16(x0.z - __uint_as_float(ah.u.y << 16),
                                 x0.w - __uint_as_float(ah.u.y & 0xffff0000u));
            al.u.z = cvt_pk_bf16(x1.x - __uint_as_float(ah.u.z << 16),
                                 x1.y - __uint_as_float(ah.u.z & 0xffff0000u));
            al.u.w = cvt_pk_bf16(x1.z - __uint_as_float(ah.u.w << 16),
                                 x1.w - __uint_as_float(ah.u.w & 0xffff0000u));

            const int ko = ks * 32 + quad * 8;
            #pragma unroll
            for (int mt = 0; mt < 4; mt++) {
                bf16x8 bh = *(const bf16x8*)&curH[(16 * mt + l15) * PITCH + ko];
                bf16x8 bl2 = *(const bf16x8*)&curL[(16 * mt + l15) * PITCH + ko];
                acc[mt] = __builtin_amdgcn_mfma_f32_16x16x32_bf16(ah.v, bh, acc[mt], 0, 0, 0);
                acc[mt] = __builtin_amdgcn_mfma_f32_16x16x32_bf16(al.v, bh, acc[mt], 0, 0, 0);
                acc[mt] = __builtin_amdgcn_mfma_f32_16x16x32_bf16(ah.v, bl2, acc[mt], 0, 0, 0);
            }
        }

        // write prefetched next tile into the other buffer
        if (wt < 7) {
            *(uint4*)&nxtH[srow0 * PITCH + sc8] = nh0;
            *(uint4*)&nxtL[srow0 * PITCH + sc8] = nl0;
            *(uint4*)&nxtH[(srow0 + 32) * PITCH + sc8] = nh1;
            *(uint4*)&nxtL[(srow0 + 32) * PITCH + sc8] = nl1;
        }
        __syncthreads();
    }

    // write G transposed as hi/lo into Xh/Xl region: Gt[m][h]
    #pragma unroll
    for (int mt = 0; mt < 4; mt++) {
        float g0 = acc[mt][0], g1 = acc[mt][1], g2 = acc[mt][2], g3 = acc[mt][3];
        unsigned int h01 = cvt_pk_bf16(g0, g1);
        unsigned int h23 = cvt_pk_bf16(g2, g3);
        float r0 = __uint_as_float(h01 << 16);
        float r1 = __uint_as_float(h01 & 0xffff0000u);
        float r2 = __uint_as_float(h23 << 16);
        float r3 = __uint_as_float(h23 & 0xffff0000u);
        unsigned int l01 = cvt_pk_bf16(g0 - r0, g1 - r1);
        unsigned int l23 = cvt_pk_bf16(g2 - r2, g3 - r3);
        int m = 16 * mt + l15;
        int h = 16 * wv + quad * 4;      // rows quad*4+r, r contiguous
        int o = m * PITCH + h;
        *(uint2*)&Xh[o] = make_uint2(h01, h23);
        *(uint2*)&Xl[o] = make_uint2(l01, l23);
    }

    // stage Fy chunk hi/lo into Fh/Fl
    {
        uint4 h0 = *(const uint4*)(FyHp + (size_t)srow0 * 512 + hbase + sc8);
        uint4 l0 = *(const uint4*)(FyLp + (size_t)srow0 * 512 + hbase + sc8);
        uint4 h1 = *(const uint4*)(FyHp + (size_t)(srow0 + 32) * 512 + hbase + sc8);
        uint4 l1 = *(const uint4*)(FyLp + (size_t)(srow0 + 32) * 512 + hbase + sc8);
        *(uint4*)&Fh[srow0 * PITCH + sc8] = h0;
        *(uint4*)&Fl[srow0 * PITCH + sc8] = l0;
        *(uint4*)&Fh[(srow0 + 32) * PITCH + sc8] = h1;
        *(uint4*)&Fl[(srow0 + 32) * PITCH + sc8] = l1;
    }
    __syncthreads();

    // GEMM2: P[n][m] = sum_h Fy[n][h] * G[h][m]
    f32x4 p[4] = {};
    #pragma unroll
    for (int ks = 0; ks < 2; ks++) {
        const int ko = ks * 32 + quad * 8;
        bf16x8 yh = *(const bf16x8*)&Fh[(16 * wv + l15) * PITCH + ko];
        bf16x8 yl = *(const bf16x8*)&Fl[(16 * wv + l15) * PITCH + ko];
        #pragma unroll
        for (int mt = 0; mt < 4; mt++) {
            bf16x8 gh = *(const bf16x8*)&Xh[(16 * mt + l15) * PITCH + ko];
            bf16x8 gl = *(const bf16x8*)&Xl[(16 * mt + l15) * PITCH + ko];
            p[mt] = __builtin_amdgcn_mfma_f32_16x16x32_bf16(yh, gh, p[mt], 0, 0, 0);
            p[mt] = __builtin_amdgcn_mfma_f32_16x16x32_bf16(yl, gh, p[mt], 0, 0, 0);
            p[mt] = __builtin_amdgcn_mfma_f32_16x16x32_bf16(yh, gl, p[mt], 0, 0, 0);
        }
    }

    const float gamma = ws[GAMMA_OFF + b];
    float* outp = out + (size_t)bc * (NOUT * NOUT);
    #pragma unroll
    for (int mt = 0; mt < 4; mt++)
        #pragma unroll
        for (int r = 0; r < 4; r++) {
            int n = 16 * wv + quad * 4 + r;
            int m = 16 * mt + l15;
            atomicAdd(&outp[n * NOUT + m], gamma * p[mt][r]);
        }
}

extern "C" void kernel_launch(void* const* d_in, const int* in_sizes, int n_in,
                              void* d_out, int out_size, void* d_ws, size_t ws_size,
                              hipStream_t stream) {
    const float* X  = (const float*)d_in[0];
    const float* Wl = (const float*)d_in[1];
    const float* bl = (const float*)d_in[2];
    float* out = (float*)d_out;
    float* ws  = (float*)d_ws;

    k_locnet<<<dim3(CHUNKS, BGROUPS), 256, 0, stream>>>(X, Wl, ws);
    k_filters<<<dim3(NOUT, B_, 2), 256, 0, stream>>>(bl, ws, out);
    k_glimpse<<<dim3(8, B_ * C_), 256, 0, stream>>>(X, ws, out);
}

// Round 11
// 202.395 us; speedup vs baseline: 2.5393x; 1.0392x over previous
//
#include <hip/hip_runtime.h>
#include <math.h>

#define B_ 32
#define C_ 3
#define H_ 512
#define W_ 512
#define NOUT 64
#define FAN (C_*H_*W_)          // 786432

// locnet decomposition
#define CHUNKS 192
#define CELEMS (FAN / CHUNKS)   // 4096
#define BGROUPS 4               // 8 batches per block

// workspace layout:
//   floats [0, 192*160): per-chunk locnet partials P[chunk][b][j]
//   floats [GAMMA_OFF, +32): gamma[b] (written by k_filters)
//   then ushort images (base = ws + PFLOATS floats):
//     FxH [32][64][512], FxL, FyH, FyL  (1,048,576 ushorts = 2MB each)
#define PPART_STRIDE 160
#define GAMMA_OFF (CHUNKS * PPART_STRIDE)   // 30720
#define PFLOATS 32768
#define FXH_U 0
#define FXL_U 1048576
#define FYH_U 2097152
#define FYL_U 3145728

typedef __bf16 bf16x8 __attribute__((ext_vector_type(8)));
typedef float f32x4 __attribute__((ext_vector_type(4)));

// round-to-nearest-even fp32 -> bf16 (as ushort) — integer emulation (exact RNE)
__device__ __forceinline__ unsigned short f2bf(float f) {
    unsigned int u = __float_as_uint(f);
    u = (u + 0x7FFFu + ((u >> 16) & 1u)) >> 16;
    return (unsigned short)u;
}
__device__ __forceinline__ float bf2f(unsigned short h) {
    return __uint_as_float(((unsigned int)h) << 16);
}
// packed fp32x2 -> bf16x2 in one VALU op (hw RNE; identical results to f2bf)
__device__ __forceinline__ unsigned int cvt_pk_bf16(float lo, float hi) {
    unsigned int r;
    asm("v_cvt_pk_bf16_f32 %0, %1, %2" : "=v"(r) : "v"(lo), "v"(hi));
    return r;
}

union BF8U { uint4 u; bf16x8 v; };

// ---------------- kernel 1: partial p[b,j] = sum_i X[b,i] * W_loc[i,j] ----------------
__global__ __launch_bounds__(256) void k_locnet(const float* __restrict__ X,
                                                const float* __restrict__ Wl,
                                                float* __restrict__ ws) {
    const int chunk = blockIdx.x;      // 0..CHUNKS-1
    const int b0 = blockIdx.y * 8;     // 0,8,16,24
    const int t = threadIdx.x;

    float acc[8][5] = {};
    const size_t base = (size_t)chunk * CELEMS;

    for (int k = t; k < CELEMS / 4; k += 256) {   // 4 iterations
        const size_t i0 = base + (size_t)k * 4;
        const float4* W4 = (const float4*)(Wl + i0 * 5);
        float4 w0 = W4[0], w1 = W4[1], w2 = W4[2], w3 = W4[3], w4 = W4[4];
        float wv[20] = {w0.x, w0.y, w0.z, w0.w,
                        w1.x, w1.y, w1.z, w1.w,
                        w2.x, w2.y, w2.z, w2.w,
                        w3.x, w3.y, w3.z, w3.w,
                        w4.x, w4.y, w4.z, w4.w};
        #pragma unroll
        for (int bb = 0; bb < 8; bb++) {
            float4 x = *(const float4*)(X + (size_t)(b0 + bb) * FAN + i0);
            float xv[4] = {x.x, x.y, x.z, x.w};
            #pragma unroll
            for (int e = 0; e < 4; e++)
                #pragma unroll
                for (int j = 0; j < 5; j++)
                    acc[bb][j] += xv[e] * wv[e * 5 + j];
        }
    }

    #pragma unroll
    for (int off = 32; off > 0; off >>= 1)
        #pragma unroll
        for (int bb = 0; bb < 8; bb++)
            #pragma unroll
            for (int j = 0; j < 5; j++)
                acc[bb][j] += __shfl_down(acc[bb][j], off);

    __shared__ float sred[4][40];
    const int wave = t >> 6, lane = t & 63;
    if (lane == 0) {
        #pragma unroll
        for (int bb = 0; bb < 8; bb++)
            #pragma unroll
            for (int j = 0; j < 5; j++)
                sred[wave][bb * 5 + j] = acc[bb][j];
    }
    __syncthreads();
    if (t < 40) {
        float s = sred[0][t] + sred[1][t] + sred[2][t] + sred[3][t];
        ws[(size_t)chunk * PPART_STRIDE + b0 * 5 + t] = s;
    }
}

// ---------------- kernel 2: reduce p, build normalized filters (bf16 hi/lo), zero out ----------------
__global__ __launch_bounds__(256) void k_filters(const float* __restrict__ bl,
                                                 float* __restrict__ ws,
                                                 float* __restrict__ out) {
    const int n = blockIdx.x;
    const int b = blockIdx.y;
    const int which = blockIdx.z;
    const int t = threadIdx.x;

    // zero a 96-float slice of out (replaces a 1.5MB memset dispatch)
    {
        const int bid = blockIdx.x + NOUT * (blockIdx.y + B_ * blockIdx.z);  // 0..4095
        if (t < 24) {
            ((float4*)out)[(size_t)bid * 24 + t] = make_float4(0.f, 0.f, 0.f, 0.f);
        }
    }

    // reduce locnet partials: p[j] = bl[j] + sum_{chunk<192} ws[chunk*160 + b*5 + j]
    float pj[5] = {0.f, 0.f, 0.f, 0.f, 0.f};
    if (t < CHUNKS) {
        const float* pr = ws + (size_t)t * PPART_STRIDE + b * 5;
        #pragma unroll
        for (int j = 0; j < 5; j++) pj[j] = pr[j];
    }
    #pragma unroll
    for (int off = 32; off > 0; off >>= 1)
        #pragma unroll
        for (int j = 0; j < 5; j++) pj[j] += __shfl_down(pj[j], off);

    __shared__ float spart[4][5];
    __shared__ float pfin[5];
    const int wave = t >> 6, lane = t & 63;
    if (lane == 0) {
        #pragma unroll
        for (int j = 0; j < 5; j++) spart[wave][j] = pj[j];
    }
    __syncthreads();
    if (t < 5) pfin[t] = spart[0][t] + spart[1][t] + spart[2][t] + spart[3][t] + bl[t];
    __syncthreads();

    const float p0 = pfin[0], p1 = pfin[1], p2 = pfin[2], p3 = pfin[3];
    if (which == 0 && n == 0 && t == 0) ws[GAMMA_OFF + b] = expf(pfin[4]);

    const float g = (which == 0) ? 32.f * (p0 + 1.f) : 32.f * (p1 + 1.f);
    const float sigma2 = expf(p2);
    const float inv2s = 0.5f / sigma2;
    const float delta = expf(p3) * (511.0f / 63.0f);
    const float mean = g + delta * ((float)n - 32.5f);

    // thread t handles elements 2t, 2t+1 (packed 4B stores)
    float d0 = (float)(2 * t) - mean;
    float f0 = expf(-d0 * d0 * inv2s);
    float d1 = (float)(2 * t + 1) - mean;
    float f1 = expf(-d1 * d1 * inv2s);

    float s = f0 + f1;
    #pragma unroll
    for (int off = 32; off > 0; off >>= 1) s += __shfl_down(s, off);
    __shared__ float sred[4];
    __shared__ float stot;
    if (lane == 0) sred[wave] = s;
    __syncthreads();
    if (t == 0) stot = sred[0] + sred[1] + sred[2] + sred[3] + 1e-4f;
    __syncthreads();
    const float scale = 1.0f / stot;

    unsigned short* wsu = (unsigned short*)(ws + PFLOATS);
    unsigned int* dstH = (unsigned int*)(wsu + (which ? FYH_U : FXH_U) + ((size_t)b * NOUT + n) * 512);
    unsigned int* dstL = (unsigned int*)(wsu + (which ? FYL_U : FXL_U) + ((size_t)b * NOUT + n) * 512);

    float v0 = f0 * scale;
    float v1 = f1 * scale;
    unsigned short h0 = f2bf(v0);
    unsigned short h1 = f2bf(v1);
    unsigned short l0 = f2bf(v0 - bf2f(h0));
    unsigned short l1 = f2bf(v1 - bf2f(h1));
    dstH[t] = (unsigned int)h0 | ((unsigned int)h1 << 16);
    dstL[t] = (unsigned int)l0 | ((unsigned int)l1 << 16);
}

// ---------------- kernel 3: MFMA glimpse (R3 structure, best verified: 203.9us) ----------------
// out[b,c] += gamma * Fy_chunk @ (X_chunk @ Fx^T), split-bf16 (hi+lo) MFMA.
// grid (8 hc, 96 bc), 256 threads = 4 waves.
// GEMM1: A (X rows) loaded DIRECT global->fragment (row = 16*wv + l15, k = quad*8)
//        — no X LDS staging. Fx chunks double-buffered in LDS: one barrier per
//        tile; next-tile filter loads issue before the MFMAs.
#define KC 64
#define PITCH 72            // ushorts per LDS row (16B-aligned rows, low-conflict)
#define TSZ (64 * PITCH)    // 4608 ushorts per array

__global__ __launch_bounds__(256) void k_glimpse(const float* __restrict__ X,
                                                 const float* __restrict__ ws,
                                                 float* __restrict__ out) {
    const int hc = blockIdx.x;   // 0..7
    const int bc = blockIdx.y;   // 0..95
    const int b = bc / 3;
    const int t = threadIdx.x;
    const int lane = t & 63;
    const int wv = t >> 6;       // 0..3
    const int l15 = lane & 15;
    const int quad = lane >> 4;  // 0..3
    const int hbase = hc * 64;

    __shared__ __align__(16) unsigned short lds[4 * TSZ];   // 36864 B
    unsigned short* Xh = lds;             // odd-tile Fx hi -> later Gt hi
    unsigned short* Xl = lds + TSZ;       // odd-tile Fx lo -> later Gt lo
    unsigned short* Fh = lds + 2 * TSZ;   // even-tile Fx hi -> later Fy hi
    unsigned short* Fl = lds + 3 * TSZ;   // even-tile Fx lo -> later Fy lo

    const float* Xp = X + (size_t)bc * (H_ * W_) + (size_t)hbase * W_;
    const unsigned short* wsu = (const unsigned short*)(ws + PFLOATS);
    const unsigned short* FxHp = wsu + FXH_U + (size_t)b * NOUT * 512;
    const unsigned short* FxLp = wsu + FXL_U + (size_t)b * NOUT * 512;
    const unsigned short* FyHp = wsu + FYH_U + (size_t)b * NOUT * 512;
    const unsigned short* FyLp = wsu + FYL_U + (size_t)b * NOUT * 512;

    // per-lane X row pointer for direct A-fragment loads
    const float* xlane = Xp + (size_t)(16 * wv + l15) * W_ + quad * 8;

    // staging index mapping (Fx/Fy chunks): thread covers 2 rows x 16B
    const int srow0 = t >> 3;              // 0..31
    const int sc8 = (t & 7) * 8;           // 0,8,..56

    // ---- prologue: stage Fx tile 0 into Fh/Fl ----
    {
        uint4 h0 = *(const uint4*)(FxHp + (size_t)srow0 * 512 + sc8);
        uint4 l0 = *(const uint4*)(FxLp + (size_t)srow0 * 512 + sc8);
        uint4 h1 = *(const uint4*)(FxHp + (size_t)(srow0 + 32) * 512 + sc8);
        uint4 l1 = *(const uint4*)(FxLp + (size_t)(srow0 + 32) * 512 + sc8);
        *(uint4*)&Fh[srow0 * PITCH + sc8] = h0;
        *(uint4*)&Fl[srow0 * PITCH + sc8] = l0;
        *(uint4*)&Fh[(srow0 + 32) * PITCH + sc8] = h1;
        *(uint4*)&Fl[(srow0 + 32) * PITCH + sc8] = l1;
    }
    __syncthreads();

    f32x4 acc[4] = {};   // G: wave rows [16wv,+16), 4 m-tiles

    #pragma unroll
    for (int wt = 0; wt < 8; wt++) {
        unsigned short* curH = (wt & 1) ? Xh : Fh;
        unsigned short* curL = (wt & 1) ? Xl : Fl;
        unsigned short* nxtH = (wt & 1) ? Fh : Xh;
        unsigned short* nxtL = (wt & 1) ? Fl : Xl;

        // issue next-tile filter loads (latency hides under the MFMAs below)
        uint4 nh0, nl0, nh1, nl1;
        if (wt < 7) {
            const int wb = (wt + 1) * KC;
            nh0 = *(const uint4*)(FxHp + (size_t)srow0 * 512 + wb + sc8);
            nl0 = *(const uint4*)(FxLp + (size_t)srow0 * 512 + wb + sc8);
            nh1 = *(const uint4*)(FxHp + (size_t)(srow0 + 32) * 512 + wb + sc8);
            nl1 = *(const uint4*)(FxLp + (size_t)(srow0 + 32) * 512 + wb + sc8);
        }

        // ---- GEMM1 MFMAs on current tile; X loaded direct to fragments ----
        #pragma unroll
        for (int ks = 0; ks < 2; ks++) {
            const float* xp = xlane + wt * KC + ks * 32;
            float4 x0 = *(const float4*)(xp);
            float4 x1 = *(const float4*)(xp + 4);
            BF8U ah, al;
            ah.u.x = cvt_pk_bf16(x0.x, x0.y);
            ah.u.y = cvt_pk_bf16(x0.z, x0.w);
            ah.u.z = cvt_pk_bf16(x1.x, x1.y);
            ah.u.w = cvt_pk_bf16(x1.z, x1.w);
            al.u.x = cvt_pk_bf16(x0.x - __uint_as_float(ah.u.x << 16),
                                 x0.y - __uint_as_float(ah.u.x & 0xffff0000u));
            al.u.y = cvt_pk_bf16(x0.z - __uint_as_float(ah.u.y << 16),
                                 x0.w - __uint_as_float(ah.u.y & 0xffff0000u));
            al.u.z = cvt_pk_bf16(x1.x - __uint_as_float(ah.u.z << 16),
                                 x1.y - __uint_as_float(ah.u.z & 0xffff0000u));
            al.u.w = cvt_pk_bf16(x1.z - __uint_as_float(ah.u.w << 16),
                                 x1.w - __uint_as_float(ah.u.w & 0xffff0000u));

            const int ko = ks * 32 + quad * 8;
            #pragma unroll
            for (int mt = 0; mt < 4; mt++) {
                bf16x8 bh = *(const bf16x8*)&curH[(16 * mt + l15) * PITCH + ko];
                bf16x8 bl2 = *(const bf16x8*)&curL[(16 * mt + l15) * PITCH + ko];
                acc[mt] = __builtin_amdgcn_mfma_f32_16x16x32_bf16(ah.v, bh, acc[mt], 0, 0, 0);
                acc[mt] = __builtin_amdgcn_mfma_f32_16x16x32_bf16(al.v, bh, acc[mt], 0, 0, 0);
                acc[mt] = __builtin_amdgcn_mfma_f32_16x16x32_bf16(ah.v, bl2, acc[mt], 0, 0, 0);
            }
        }

        // write prefetched next tile into the other buffer
        if (wt < 7) {
            *(uint4*)&nxtH[srow0 * PITCH + sc8] = nh0;
            *(uint4*)&nxtL[srow0 * PITCH + sc8] = nl0;
            *(uint4*)&nxtH[(srow0 + 32) * PITCH + sc8] = nh1;
            *(uint4*)&nxtL[(srow0 + 32) * PITCH + sc8] = nl1;
        }
        __syncthreads();
    }

    // write G transposed as hi/lo into Xh/Xl region: Gt[m][h]
    #pragma unroll
    for (int mt = 0; mt < 4; mt++) {
        float g0 = acc[mt][0], g1 = acc[mt][1], g2 = acc[mt][2], g3 = acc[mt][3];
        unsigned int h01 = cvt_pk_bf16(g0, g1);
        unsigned int h23 = cvt_pk_bf16(g2, g3);
        float r0 = __uint_as_float(h01 << 16);
        float r1 = __uint_as_float(h01 & 0xffff0000u);
        float r2 = __uint_as_float(h23 << 16);
        float r3 = __uint_as_float(h23 & 0xffff0000u);
        unsigned int l01 = cvt_pk_bf16(g0 - r0, g1 - r1);
        unsigned int l23 = cvt_pk_bf16(g2 - r2, g3 - r3);
        int m = 16 * mt + l15;
        int h = 16 * wv + quad * 4;      // rows quad*4+r, r contiguous
        int o = m * PITCH + h;
        *(uint2*)&Xh[o] = make_uint2(h01, h23);
        *(uint2*)&Xl[o] = make_uint2(l01, l23);
    }

    // stage Fy chunk hi/lo into Fh/Fl
    {
        uint4 h0 = *(const uint4*)(FyHp + (size_t)srow0 * 512 + hbase + sc8);
        uint4 l0 = *(const uint4*)(FyLp + (size_t)srow0 * 512 + hbase + sc8);
        uint4 h1 = *(const uint4*)(FyHp + (size_t)(srow0 + 32) * 512 + hbase + sc8);
        uint4 l1 = *(const uint4*)(FyLp + (size_t)(srow0 + 32) * 512 + hbase + sc8);
        *(uint4*)&Fh[srow0 * PITCH + sc8] = h0;
        *(uint4*)&Fl[srow0 * PITCH + sc8] = l0;
        *(uint4*)&Fh[(srow0 + 32) * PITCH + sc8] = h1;
        *(uint4*)&Fl[(srow0 + 32) * PITCH + sc8] = l1;
    }
    __syncthreads();

    // GEMM2: P[n][m] = sum_h Fy[n][h] * G[h][m]
    f32x4 p[4] = {};
    #pragma unroll
    for (int ks = 0; ks < 2; ks++) {
        const int ko = ks * 32 + quad * 8;
        bf16x8 yh = *(const bf16x8*)&Fh[(16 * wv + l15) * PITCH + ko];
        bf16x8 yl = *(const bf16x8*)&Fl[(16 * wv + l15) * PITCH + ko];
        #pragma unroll
        for (int mt = 0; mt < 4; mt++) {
            bf16x8 gh = *(const bf16x8*)&Xh[(16 * mt + l15) * PITCH + ko];
            bf16x8 gl = *(const bf16x8*)&Xl[(16 * mt + l15) * PITCH + ko];
            p[mt] = __builtin_amdgcn_mfma_f32_16x16x32_bf16(yh, gh, p[mt], 0, 0, 0);
            p[mt] = __builtin_amdgcn_mfma_f32_16x16x32_bf16(yl, gh, p[mt], 0, 0, 0);
            p[mt] = __builtin_amdgcn_mfma_f32_16x16x32_bf16(yh, gl, p[mt], 0, 0, 0);
        }
    }

    const float gamma = ws[GAMMA_OFF + b];
    float* outp = out + (size_t)bc * (NOUT * NOUT);
    #pragma unroll
    for (int mt = 0; mt < 4; mt++)
        #pragma unroll
        for (int r = 0; r < 4; r++) {
            int n = 16 * wv + quad * 4 + r;
            int m = 16 * mt + l15;
            atomicAdd(&outp[n * NOUT + m], gamma * p[mt][r]);
        }
}

extern "C" void kernel_launch(void* const* d_in, const int* in_sizes, int n_in,
                              void* d_out, int out_size, void* d_ws, size_t ws_size,
                              hipStream_t stream) {
    const float* X  = (const float*)d_in[0];
    const float* Wl = (const float*)d_in[1];
    const float* bl = (const float*)d_in[2];
    float* out = (float*)d_out;
    float* ws  = (float*)d_ws;

    k_locnet<<<dim3(CHUNKS, BGROUPS), 256, 0, stream>>>(X, Wl, ws);
    k_filters<<<dim3(NOUT, B_, 2), 256, 0, stream>>>(bl, ws, out);
    k_glimpse<<<dim3(8, B_ * C_), 256, 0, stream>>>(X, ws, out);
}

// Round 12
// 199.548 us; speedup vs baseline: 2.5755x; 1.0143x over previous
//
#include <hip/hip_runtime.h>
#include <math.h>

#define B_ 32
#define C_ 3
#define H_ 512
#define W_ 512
#define NOUT 64
#define FAN (C_*H_*W_)          // 786432

// locnet decomposition
#define CHUNKS 192
#define CELEMS (FAN / CHUNKS)   // 4096
#define BGROUPS 4               // 8 batches per block

// workspace layout:
//   floats [0, 192*160): per-chunk locnet partials P[chunk][b][j]
//   floats [GAMMA_OFF, +32): gamma[b] (written by k_filters)
//   then ushort images (base = ws + PFLOATS floats):
//     FxH [32][64][512], (FxL slot unused), FyH, FyL  (1,048,576 ushorts each)
#define PPART_STRIDE 160
#define GAMMA_OFF (CHUNKS * PPART_STRIDE)   // 30720
#define PFLOATS 32768
#define FXH_U 0
#define FXL_U 1048576
#define FYH_U 2097152
#define FYL_U 3145728

typedef __bf16 bf16x8 __attribute__((ext_vector_type(8)));
typedef float f32x4 __attribute__((ext_vector_type(4)));

// round-to-nearest-even fp32 -> bf16 (as ushort) — integer emulation (exact RNE)
__device__ __forceinline__ unsigned short f2bf(float f) {
    unsigned int u = __float_as_uint(f);
    u = (u + 0x7FFFu + ((u >> 16) & 1u)) >> 16;
    return (unsigned short)u;
}
__device__ __forceinline__ float bf2f(unsigned short h) {
    return __uint_as_float(((unsigned int)h) << 16);
}
// packed fp32x2 -> bf16x2 in one VALU op (hw RNE; identical results to f2bf)
__device__ __forceinline__ unsigned int cvt_pk_bf16(float lo, float hi) {
    unsigned int r;
    asm("v_cvt_pk_bf16_f32 %0, %1, %2" : "=v"(r) : "v"(lo), "v"(hi));
    return r;
}

union BF8U { uint4 u; bf16x8 v; };

// ---------------- kernel 1: partial p[b,j] = sum_i X[b,i] * W_loc[i,j] ----------------
__global__ __launch_bounds__(256) void k_locnet(const float* __restrict__ X,
                                                const float* __restrict__ Wl,
                                                float* __restrict__ ws) {
    const int chunk = blockIdx.x;      // 0..CHUNKS-1
    const int b0 = blockIdx.y * 8;     // 0,8,16,24
    const int t = threadIdx.x;

    float acc[8][5] = {};
    const size_t base = (size_t)chunk * CELEMS;

    for (int k = t; k < CELEMS / 4; k += 256) {   // 4 iterations
        const size_t i0 = base + (size_t)k * 4;
        const float4* W4 = (const float4*)(Wl + i0 * 5);
        float4 w0 = W4[0], w1 = W4[1], w2 = W4[2], w3 = W4[3], w4 = W4[4];
        float wv[20] = {w0.x, w0.y, w0.z, w0.w,
                        w1.x, w1.y, w1.z, w1.w,
                        w2.x, w2.y, w2.z, w2.w,
                        w3.x, w3.y, w3.z, w3.w,
                        w4.x, w4.y, w4.z, w4.w};
        #pragma unroll
        for (int bb = 0; bb < 8; bb++) {
            float4 x = *(const float4*)(X + (size_t)(b0 + bb) * FAN + i0);
            float xv[4] = {x.x, x.y, x.z, x.w};
            #pragma unroll
            for (int e = 0; e < 4; e++)
                #pragma unroll
                for (int j = 0; j < 5; j++)
                    acc[bb][j] += xv[e] * wv[e * 5 + j];
        }
    }

    #pragma unroll
    for (int off = 32; off > 0; off >>= 1)
        #pragma unroll
        for (int bb = 0; bb < 8; bb++)
            #pragma unroll
            for (int j = 0; j < 5; j++)
                acc[bb][j] += __shfl_down(acc[bb][j], off);

    __shared__ float sred[4][40];
    const int wave = t >> 6, lane = t & 63;
    if (lane == 0) {
        #pragma unroll
        for (int bb = 0; bb < 8; bb++)
            #pragma unroll
            for (int j = 0; j < 5; j++)
                sred[wave][bb * 5 + j] = acc[bb][j];
    }
    __syncthreads();
    if (t < 40) {
        float s = sred[0][t] + sred[1][t] + sred[2][t] + sred[3][t];
        ws[(size_t)chunk * PPART_STRIDE + b0 * 5 + t] = s;
    }
}

// ---------------- kernel 2: reduce p, build normalized filters, zero out ----------------
// Fx: bf16 hi only. Fy: hi + lo (lo still used by GEMM2's correction terms).
__global__ __launch_bounds__(256) void k_filters(const float* __restrict__ bl,
                                                 float* __restrict__ ws,
                                                 float* __restrict__ out) {
    const int n = blockIdx.x;
    const int b = blockIdx.y;
    const int which = blockIdx.z;
    const int t = threadIdx.x;

    // zero a 96-float slice of out (replaces a 1.5MB memset dispatch)
    {
        const int bid = blockIdx.x + NOUT * (blockIdx.y + B_ * blockIdx.z);  // 0..4095
        if (t < 24) {
            ((float4*)out)[(size_t)bid * 24 + t] = make_float4(0.f, 0.f, 0.f, 0.f);
        }
    }

    // reduce locnet partials: p[j] = bl[j] + sum_{chunk<192} ws[chunk*160 + b*5 + j]
    float pj[5] = {0.f, 0.f, 0.f, 0.f, 0.f};
    if (t < CHUNKS) {
        const float* pr = ws + (size_t)t * PPART_STRIDE + b * 5;
        #pragma unroll
        for (int j = 0; j < 5; j++) pj[j] = pr[j];
    }
    #pragma unroll
    for (int off = 32; off > 0; off >>= 1)
        #pragma unroll
        for (int j = 0; j < 5; j++) pj[j] += __shfl_down(pj[j], off);

    __shared__ float spart[4][5];
    __shared__ float pfin[5];
    const int wave = t >> 6, lane = t & 63;
    if (lane == 0) {
        #pragma unroll
        for (int j = 0; j < 5; j++) spart[wave][j] = pj[j];
    }
    __syncthreads();
    if (t < 5) pfin[t] = spart[0][t] + spart[1][t] + spart[2][t] + spart[3][t] + bl[t];
    __syncthreads();

    const float p0 = pfin[0], p1 = pfin[1], p2 = pfin[2], p3 = pfin[3];
    if (which == 0 && n == 0 && t == 0) ws[GAMMA_OFF + b] = expf(pfin[4]);

    const float g = (which == 0) ? 32.f * (p0 + 1.f) : 32.f * (p1 + 1.f);
    const float sigma2 = expf(p2);
    const float inv2s = 0.5f / sigma2;
    const float delta = expf(p3) * (511.0f / 63.0f);
    const float mean = g + delta * ((float)n - 32.5f);

    // thread t handles elements 2t, 2t+1 (packed 4B stores)
    float d0 = (float)(2 * t) - mean;
    float f0 = expf(-d0 * d0 * inv2s);
    float d1 = (float)(2 * t + 1) - mean;
    float f1 = expf(-d1 * d1 * inv2s);

    float s = f0 + f1;
    #pragma unroll
    for (int off = 32; off > 0; off >>= 1) s += __shfl_down(s, off);
    __shared__ float sred[4];
    __shared__ float stot;
    if (lane == 0) sred[wave] = s;
    __syncthreads();
    if (t == 0) stot = sred[0] + sred[1] + sred[2] + sred[3] + 1e-4f;
    __syncthreads();
    const float scale = 1.0f / stot;

    unsigned short* wsu = (unsigned short*)(ws + PFLOATS);
    unsigned int* dstH = (unsigned int*)(wsu + (which ? FYH_U : FXH_U) + ((size_t)b * NOUT + n) * 512);

    float v0 = f0 * scale;
    float v1 = f1 * scale;
    unsigned short h0 = f2bf(v0);
    unsigned short h1 = f2bf(v1);
    dstH[t] = (unsigned int)h0 | ((unsigned int)h1 << 16);
    if (which) {   // Fy lo still consumed by GEMM2
        unsigned int* dstL = (unsigned int*)(wsu + FYL_U + ((size_t)b * NOUT + n) * 512);
        unsigned short l0 = f2bf(v0 - bf2f(h0));
        unsigned short l1 = f2bf(v1 - bf2f(h1));
        dstL[t] = (unsigned int)l0 | ((unsigned int)l1 << 16);
    }
}

// ---------------- kernel 3: MFMA glimpse (R3 structure; GEMM1 trimmed to hi-hi) ----------------
// out[b,c] += gamma * Fy_chunk @ (X_chunk @ Fx^T).
// GEMM1: hi(X)·hi(Fx) only — X-lo and Fx-lo correction terms dropped (arithmetic-
//   only trim of the 202.4us champion; error budget: +~0.014 each on 0.144 thr).
// GEMM2: full hi/lo corrections on G and Fy (unchanged).
// Buffers, staging maps, barriers identical to the verified R3 kernel.
#define KC 64
#define PITCH 72            // ushorts per LDS row (16B-aligned rows, low-conflict)
#define TSZ (64 * PITCH)    // 4608 ushorts per array

__global__ __launch_bounds__(256) void k_glimpse(const float* __restrict__ X,
                                                 const float* __restrict__ ws,
                                                 float* __restrict__ out) {
    const int hc = blockIdx.x;   // 0..7
    const int bc = blockIdx.y;   // 0..95
    const int b = bc / 3;
    const int t = threadIdx.x;
    const int lane = t & 63;
    const int wv = t >> 6;       // 0..3
    const int l15 = lane & 15;
    const int quad = lane >> 4;  // 0..3
    const int hbase = hc * 64;

    __shared__ __align__(16) unsigned short lds[4 * TSZ];   // 36864 B
    unsigned short* Xh = lds;             // odd-tile Fx hi -> later Gt hi
    unsigned short* Xl = lds + TSZ;       // (loop: unused)  -> later Gt lo
    unsigned short* Fh = lds + 2 * TSZ;   // even-tile Fx hi -> later Fy hi
    unsigned short* Fl = lds + 3 * TSZ;   // (loop: unused)  -> later Fy lo

    const float* Xp = X + (size_t)bc * (H_ * W_) + (size_t)hbase * W_;
    const unsigned short* wsu = (const unsigned short*)(ws + PFLOATS);
    const unsigned short* FxHp = wsu + FXH_U + (size_t)b * NOUT * 512;
    const unsigned short* FyHp = wsu + FYH_U + (size_t)b * NOUT * 512;
    const unsigned short* FyLp = wsu + FYL_U + (size_t)b * NOUT * 512;

    // per-lane X row pointer for direct A-fragment loads
    const float* xlane = Xp + (size_t)(16 * wv + l15) * W_ + quad * 8;

    // staging index mapping (Fx/Fy chunks): thread covers 2 rows x 16B
    const int srow0 = t >> 3;              // 0..31
    const int sc8 = (t & 7) * 8;           // 0,8,..56

    // ---- prologue: stage Fx tile 0 (hi) into Fh ----
    {
        uint4 h0 = *(const uint4*)(FxHp + (size_t)srow0 * 512 + sc8);
        uint4 h1 = *(const uint4*)(FxHp + (size_t)(srow0 + 32) * 512 + sc8);
        *(uint4*)&Fh[srow0 * PITCH + sc8] = h0;
        *(uint4*)&Fh[(srow0 + 32) * PITCH + sc8] = h1;
    }
    __syncthreads();

    f32x4 acc[4] = {};   // G: wave rows [16wv,+16), 4 m-tiles

    #pragma unroll
    for (int wt = 0; wt < 8; wt++) {
        unsigned short* curH = (wt & 1) ? Xh : Fh;
        unsigned short* nxtH = (wt & 1) ? Fh : Xh;

        // issue next-tile filter loads (latency hides under the MFMAs below)
        uint4 nh0, nh1;
        if (wt < 7) {
            const int wb = (wt + 1) * KC;
            nh0 = *(const uint4*)(FxHp + (size_t)srow0 * 512 + wb + sc8);
            nh1 = *(const uint4*)(FxHp + (size_t)(srow0 + 32) * 512 + wb + sc8);
        }

        // ---- GEMM1 MFMAs on current tile; X loaded direct to hi fragments ----
        #pragma unroll
        for (int ks = 0; ks < 2; ks++) {
            const float* xp = xlane + wt * KC + ks * 32;
            float4 x0 = *(const float4*)(xp);
            float4 x1 = *(const float4*)(xp + 4);
            BF8U ah;
            ah.u.x = cvt_pk_bf16(x0.x, x0.y);
            ah.u.y = cvt_pk_bf16(x0.z, x0.w);
            ah.u.z = cvt_pk_bf16(x1.x, x1.y);
            ah.u.w = cvt_pk_bf16(x1.z, x1.w);

            const int ko = ks * 32 + quad * 8;
            #pragma unroll
            for (int mt = 0; mt < 4; mt++) {
                bf16x8 bh = *(const bf16x8*)&curH[(16 * mt + l15) * PITCH + ko];
                acc[mt] = __builtin_amdgcn_mfma_f32_16x16x32_bf16(ah.v, bh, acc[mt], 0, 0, 0);
            }
        }

        // write prefetched next tile into the other buffer
        if (wt < 7) {
            *(uint4*)&nxtH[srow0 * PITCH + sc8] = nh0;
            *(uint4*)&nxtH[(srow0 + 32) * PITCH + sc8] = nh1;
        }
        __syncthreads();
    }

    // write G transposed as hi/lo into Xh/Xl region: Gt[m][h]
    #pragma unroll
    for (int mt = 0; mt < 4; mt++) {
        float g0 = acc[mt][0], g1 = acc[mt][1], g2 = acc[mt][2], g3 = acc[mt][3];
        unsigned int h01 = cvt_pk_bf16(g0, g1);
        unsigned int h23 = cvt_pk_bf16(g2, g3);
        float r0 = __uint_as_float(h01 << 16);
        float r1 = __uint_as_float(h01 & 0xffff0000u);
        float r2 = __uint_as_float(h23 << 16);
        float r3 = __uint_as_float(h23 & 0xffff0000u);
        unsigned int l01 = cvt_pk_bf16(g0 - r0, g1 - r1);
        unsigned int l23 = cvt_pk_bf16(g2 - r2, g3 - r3);
        int m = 16 * mt + l15;
        int h = 16 * wv + quad * 4;      // rows quad*4+r, r contiguous
        int o = m * PITCH + h;
        *(uint2*)&Xh[o] = make_uint2(h01, h23);
        *(uint2*)&Xl[o] = make_uint2(l01, l23);
    }

    // stage Fy chunk hi/lo into Fh/Fl
    {
        uint4 h0 = *(const uint4*)(FyHp + (size_t)srow0 * 512 + hbase + sc8);
        uint4 l0 = *(const uint4*)(FyLp + (size_t)srow0 * 512 + hbase + sc8);
        uint4 h1 = *(const uint4*)(FyHp + (size_t)(srow0 + 32) * 512 + hbase + sc8);
        uint4 l1 = *(const uint4*)(FyLp + (size_t)(srow0 + 32) * 512 + hbase + sc8);
        *(uint4*)&Fh[srow0 * PITCH + sc8] = h0;
        *(uint4*)&Fl[srow0 * PITCH + sc8] = l0;
        *(uint4*)&Fh[(srow0 + 32) * PITCH + sc8] = h1;
        *(uint4*)&Fl[(srow0 + 32) * PITCH + sc8] = l1;
    }
    __syncthreads();

    // GEMM2: P[n][m] = sum_h Fy[n][h] * G[h][m]  (full hi/lo corrections)
    f32x4 p[4] = {};
    #pragma unroll
    for (int ks = 0; ks < 2; ks++) {
        const int ko = ks * 32 + quad * 8;
        bf16x8 yh = *(const bf16x8*)&Fh[(16 * wv + l15) * PITCH + ko];
        bf16x8 yl = *(const bf16x8*)&Fl[(16 * wv + l15) * PITCH + ko];
        #pragma unroll
        for (int mt = 0; mt < 4; mt++) {
            bf16x8 gh = *(const bf16x8*)&Xh[(16 * mt + l15) * PITCH + ko];
            bf16x8 gl = *(const bf16x8*)&Xl[(16 * mt + l15) * PITCH + ko];
            p[mt] = __builtin_amdgcn_mfma_f32_16x16x32_bf16(yh, gh, p[mt], 0, 0, 0);
            p[mt] = __builtin_amdgcn_mfma_f32_16x16x32_bf16(yl, gh, p[mt], 0, 0, 0);
            p[mt] = __builtin_amdgcn_mfma_f32_16x16x32_bf16(yh, gl, p[mt], 0, 0, 0);
        }
    }

    const float gamma = ws[GAMMA_OFF + b];
    float* outp = out + (size_t)bc * (NOUT * NOUT);
    #pragma unroll
    for (int mt = 0; mt < 4; mt++)
        #pragma unroll
        for (int r = 0; r < 4; r++) {
            int n = 16 * wv + quad * 4 + r;
            int m = 16 * mt + l15;
            atomicAdd(&outp[n * NOUT + m], gamma * p[mt][r]);
        }
}

extern "C" void kernel_launch(void* const* d_in, const int* in_sizes, int n_in,
                              void* d_out, int out_size, void* d_ws, size_t ws_size,
                              hipStream_t stream) {
    const float* X  = (const float*)d_in[0];
    const float* Wl = (const float*)d_in[1];
    const float* bl = (const float*)d_in[2];
    float* out = (float*)d_out;
    float* ws  = (float*)d_ws;

    k_locnet<<<dim3(CHUNKS, BGROUPS), 256, 0, stream>>>(X, Wl, ws);
    k_filters<<<dim3(NOUT, B_, 2), 256, 0, stream>>>(bl, ws, out);
    k_glimpse<<<dim3(8, B_ * C_), 256, 0, stream>>>(X, ws, out);
}